// Round 6
// baseline (158.638 us; speedup 1.0000x reference)
//
#include <hip/hip_runtime.h>

#define SM 1028
#define D_ 256
#define S_ 1024
#define B_ 8

// Kernel 1: c[b,d,i] = sum_{w<i} x[b,d,w] * weight[d,i,w]; y = x*(1+relu(c))
// grid: 1024 blocks = 256 d * 4 row-blocks (256 rows). block: 256 thr = 4 waves.
// Wave = 4 groups x 16 lanes. Group m owns phase-class-m rows
// (r0 = wb+m+16*qq + {0,4,8,12}; row stride 4112 B = 16 mod 64 so all share
// byte phase 16m). Chunk grid shifted by a=(16-4m)&15: every group-span is a
// 256 B line-aligned contiguous run of ONE row (4 full lines per load inst,
// 256 streams/CU) -- round-1's DRAM page locality + round-4's zero straddle.
// xb LDS windows of the 4 groups union to 76 floats -> <=3 addr/bank (~free).
// Reduction: radix-16 butterfly once per 16-row quad. Causal tail: 2
// predicated epilogue chunks + predicated prologue for [0,a).
__global__ __launch_bounds__(256, 4)
void lie_mix_kernel(const float* __restrict__ x, const float* __restrict__ weight,
                    float* __restrict__ y) {
  int bid = blockIdx.x;
  int d = bid & 255;
  int bi = 3 - (bid >> 8);    // heavy row-blocks get low blockIdx
  int i0 = bi << 8;           // block rows: [i0, i0+256)

  __shared__ __align__(16) float xs[B_][1040];  // 16-elem zeroed pad per row

  int t = threadIdx.x;
#pragma unroll
  for (int bb = 0; bb < B_; ++bb) {
    const float4* src = (const float4*)(x + ((size_t)bb * D_ + d) * S_);
    *(float4*)&xs[bb][t << 2] = src[t];
  }
  if (t < 32)
    *(float4*)&xs[t >> 2][1024 + ((t & 3) << 2)] = make_float4(0.f, 0.f, 0.f, 0.f);
  __syncthreads();

  int lane = t & 63;
  int wid = t >> 6;
  int wb = i0 + (wid << 6);          // wave rows: [wb, wb+64)
  int m = lane >> 4;                 // group = phase class (rows == m mod 4)
  int j = lane & 15;                 // lane within 16-lane group
  int a = (16 - (m << 2)) & 15;      // aligned chunk-grid shift (elements)
  int j4 = j << 2;

  for (int qq = 0; qq < 4; ++qq) {
    int r0 = wb + m + (qq << 4);     // group rows: r0 + 4k, k=0..3
    const float* wptr = weight + ((size_t)d * SM + r0) * SM + a + j4;

    float acc[4][8];
#pragma unroll
    for (int k = 0; k < 4; ++k)
#pragma unroll
      for (int b = 0; b < 8; ++b) acc[k][b] = 0.f;

    // ---- prologue: elements [0, a), window [a-64, a) (line-aligned) ----
    if (a > 0) {
      int e_s = a - 64 + j4;
      if (e_s >= 0) {                // float4 fully within [0, a)
        float4 xb[8];
#pragma unroll
        for (int b = 0; b < 8; ++b) xb[b] = *(const float4*)&xs[b][e_s];
#pragma unroll
        for (int k = 0; k < 4; ++k) {
          int rk = r0 + (k << 2);
          float4 v = make_float4(0.f, 0.f, 0.f, 0.f);
          if (e_s < rk) v = *(const float4*)(wptr - 64 + (size_t)(k * 4) * SM);
          if (e_s + 1 >= rk) v.y = 0.f;
          if (e_s + 2 >= rk) v.z = 0.f;
          if (e_s + 3 >= rk) v.w = 0.f;
#pragma unroll
          for (int b = 0; b < 8; ++b)
            acc[k][b] += xb[b].x * v.x + xb[b].y * v.y + xb[b].z * v.z + xb[b].w * v.w;
        }
      }
    }

    // ---- main loop: full 64-elem chunks; each k-load = 256 B contiguous ----
    int F = (r0 - a) >> 6;
    if (F < 0) F = 0;
    for (int c = 0; c < F; ++c) {
      int w0 = c << 6;
      float4 wc[4];
#pragma unroll
      for (int k = 0; k < 4; ++k)
        wc[k] = *(const float4*)(wptr + (size_t)(k * 4) * SM + w0);
      int e = a + w0 + j4;
#pragma unroll
      for (int b = 0; b < 8; ++b) {
        float4 xb = *(const float4*)&xs[b][e];
#pragma unroll
        for (int k = 0; k < 4; ++k) {
          acc[k][b] += xb.x * wc[k].x + xb.y * wc[k].y + xb.z * wc[k].z + xb.w * wc[k].w;
        }
      }
    }

    // ---- epilogue: 2 predicated chunks cover [a+64F, rk) for all 4 rows ----
#pragma unroll
    for (int ec = 0; ec < 2; ++ec) {
      int w0 = (F + ec) << 6;
      int e_s = a + w0 + j4;
      int e_x = e_s > 1024 ? 1024 : e_s;  // clamp into zeroed pad
      float4 wm[4];
#pragma unroll
      for (int k = 0; k < 4; ++k) {
        int rk = r0 + (k << 2);
        float4 v = make_float4(0.f, 0.f, 0.f, 0.f);
        if (e_s < rk) v = *(const float4*)(wptr + (size_t)(k * 4) * SM + w0);
        if (e_s + 1 >= rk) v.y = 0.f;
        if (e_s + 2 >= rk) v.z = 0.f;
        if (e_s + 3 >= rk) v.w = 0.f;
        wm[k] = v;
      }
#pragma unroll
      for (int b = 0; b < 8; ++b) {
        float4 xb = *(const float4*)&xs[b][e_x];
#pragma unroll
        for (int k = 0; k < 4; ++k) {
          acc[k][b] += xb.x * wm[k].x + xb.y * wm[k].y + xb.z * wm[k].z + xb.w * wm[k].w;
        }
      }
    }

    // ---- radix-16 butterfly (xor 1,2,4,8 stay within the 16-lane group) ----
#pragma unroll
    for (int s = 1; s < 16; s <<= 1)
#pragma unroll
      for (int k = 0; k < 4; ++k)
#pragma unroll
        for (int b = 0; b < 8; ++b)
          acc[k][b] += __shfl_xor(acc[k][b], s, 64);

    // ---- store: lane j -> row r0+4*(j&3), batches j>>2 and (j>>2)+4 ----
    {
      int kk = j & 3, bb = j >> 2;
      float v0 = 0.f, v1 = 0.f;
#pragma unroll
      for (int k = 0; k < 4; ++k)
#pragma unroll
        for (int b = 0; b < 4; ++b) {
          bool sel = (kk == k) && (bb == b);
          v0 = sel ? acc[k][b] : v0;
          v1 = sel ? acc[k][b + 4] : v1;
        }
      int r = r0 + (kk << 2);
      float xv0 = xs[bb][r], xv1 = xs[bb + 4][r];
      y[((size_t)bb * D_ + d) * S_ + r] = xv0 * (1.f + fmaxf(v0, 0.f));
      y[((size_t)(bb + 4) * D_ + d) * S_ + r] = xv1 * (1.f + fmaxf(v1, 0.f));
    }
  }
}

// Kernel 2: LayerNorm over channel axis d (size 256) per (b, s).
__global__ __launch_bounds__(256)
void ln_kernel(const float* __restrict__ y, const float* __restrict__ gamma,
               const float* __restrict__ beta, float* __restrict__ out) {
  __shared__ float tile[D_][33];
  __shared__ float ps[8][32];
  __shared__ float pq[8][32];
  __shared__ float mu[32];
  __shared__ float rs[32];
  int b = blockIdx.x >> 5;
  int s0 = (blockIdx.x & 31) << 5;
  int t = threadIdx.x;
  int sj = t & 31, dq = t >> 5;
  for (int dd = dq; dd < D_; dd += 8)
    tile[dd][sj] = y[((size_t)b * D_ + dd) * S_ + s0 + sj];
  __syncthreads();
  float sm = 0.f, sq = 0.f;
#pragma unroll 8
  for (int r = 0; r < 32; ++r) {
    float v = tile[dq * 32 + r][sj];
    sm += v;
    sq += v * v;
  }
  ps[dq][sj] = sm;
  pq[dq][sj] = sq;
  __syncthreads();
  if (t < 32) {
    float S = 0.f, Q = 0.f;
#pragma unroll
    for (int qq = 0; qq < 8; ++qq) { S += ps[qq][t]; Q += pq[qq][t]; }
    float mm = S * (1.f / 256.f);
    float var = Q * (1.f / 256.f) - mm * mm;
    mu[t] = mm;
    rs[t] = rsqrtf(var + 1e-5f);
  }
  __syncthreads();
  for (int dd = dq; dd < D_; dd += 8) {
    float v = tile[dd][sj];
    out[((size_t)b * D_ + dd) * S_ + s0 + sj] =
        (v - mu[sj]) * rs[sj] * gamma[dd] + beta[dd];
  }
}

extern "C" void kernel_launch(void* const* d_in, const int* in_sizes, int n_in,
                              void* d_out, int out_size, void* d_ws, size_t ws_size,
                              hipStream_t stream) {
  const float* x = (const float*)d_in[0];
  const float* weight = (const float*)d_in[1];
  const float* gamma = (const float*)d_in[2];
  const float* beta = (const float*)d_in[3];
  float* out = (float*)d_out;
  float* y = (float*)d_ws;  // 8*256*1024 f32 = 8 MB scratch

  lie_mix_kernel<<<1024, 256, 0, stream>>>(x, weight, y);
  ln_kernel<<<256, 256, 0, stream>>>(y, gamma, beta, out);
}

// Round 7
// 135.624 us; speedup vs baseline: 1.1697x; 1.1697x over previous
//
#include <hip/hip_runtime.h>

#define SM 1028
#define D_ 256
#define S_ 1024
#define B_ 8

// Kernel 1: c[b,d,i] = sum_{w<i} x[b,d,w] * weight[d,i,w]; y = x*(1+relu(c))
// grid: 4096 = 256 d * 16 row-blocks (64 rows), heavy-first. block: 256 thr =
// 4 waves, NO LDS, NO barrier. Wave = 4 groups x 16 lanes; group owns 4
// CONSECUTIVE rows (adjacent chunks of a row reuse straddled lines via L1/L2).
// x read directly from global (L2-resident, xb traffic = 0.5x weight).
// Zero LDS + ~90 VGPR -> 20 waves/CU (launch_bounds(256,5)) for 1.3x more
// reads in flight (latency-occupancy hypothesis). Radix-16 shfl reduce,
// float4 y stores.
__global__ __launch_bounds__(256, 5)
void lie_mix_kernel(const float* __restrict__ x, const float* __restrict__ weight,
                    float* __restrict__ y) {
  int bid = blockIdx.x;
  int d = bid & 255;
  int bi = 15 - (bid >> 8);   // heavy (large i0) blocks get low blockIdx
  int i0 = bi << 6;           // block rows: [i0, i0+64)

  int t = threadIdx.x;
  int lane = t & 63;
  int wid = t >> 6;
  int g = lane >> 4;                 // group within wave
  int jj = lane & 15;                // lane within group
  int j4 = jj << 2;
  int rbase = i0 + (wid << 4) + (g << 2);  // 4 consecutive rows

  const float* wbase = weight + ((size_t)d * SM + rbase) * SM + j4;
  const float* xd = x + ((size_t)d << 10);   // x[b][d][*] = xd + (b<<20 elems? no)

  float acc[4][8];
#pragma unroll
  for (int k = 0; k < 4; ++k)
#pragma unroll
    for (int b = 0; b < 8; ++b) acc[k][b] = 0.f;

  int F = i0 >> 6;  // full 64-elem chunks

  for (int c = 0; c < F; ++c) {
    int w0 = c << 6;
    float4 wc[4];
#pragma unroll
    for (int k = 0; k < 4; ++k)
      wc[k] = *(const float4*)(wbase + (size_t)k * SM + w0);
    // batches in two halves of 4 to bound register pressure
#pragma unroll
    for (int h = 0; h < 2; ++h) {
      float4 xb[4];
#pragma unroll
      for (int b = 0; b < 4; ++b)
        xb[b] = *(const float4*)(xd + ((size_t)((h * 4 + b) << 8) << 10) + w0 + j4);
#pragma unroll
      for (int b = 0; b < 4; ++b) {
        int bb = h * 4 + b;
#pragma unroll
        for (int k = 0; k < 4; ++k) {
          acc[k][bb] += xb[b].x * wc[k].x + xb[b].y * wc[k].y +
                        xb[b].z * wc[k].z + xb[b].w * wc[k].w;
        }
      }
    }
  }

  // final masked chunk: w in [i0, i0+64); element e valid iff e < row-i0
  {
    int w0 = i0;
    int lim0 = (wid << 4) + (g << 2);  // rbase - i0
    float4 wm[4];
#pragma unroll
    for (int k = 0; k < 4; ++k) {
      int lim = lim0 + k;
      float4 v = make_float4(0.f, 0.f, 0.f, 0.f);
      if (j4 < lim) v = *(const float4*)(wbase + (size_t)k * SM + w0);
      if (j4 + 1 >= lim) v.y = 0.f;
      if (j4 + 2 >= lim) v.z = 0.f;
      if (j4 + 3 >= lim) v.w = 0.f;
      wm[k] = v;
    }
#pragma unroll
    for (int h = 0; h < 2; ++h) {
      float4 xb[4];
#pragma unroll
      for (int b = 0; b < 4; ++b)
        xb[b] = *(const float4*)(xd + ((size_t)((h * 4 + b) << 8) << 10) + w0 + j4);
#pragma unroll
      for (int b = 0; b < 4; ++b) {
        int bb = h * 4 + b;
#pragma unroll
        for (int k = 0; k < 4; ++k) {
          acc[k][bb] += xb[b].x * wm[k].x + xb[b].y * wm[k].y +
                        xb[b].z * wm[k].z + xb[b].w * wm[k].w;
        }
      }
    }
  }

  // radix-16 butterfly (xor 1,2,4,8 stay within the 16-lane group)
#pragma unroll
  for (int s = 1; s < 16; s <<= 1)
#pragma unroll
    for (int k = 0; k < 4; ++k)
#pragma unroll
      for (int b = 0; b < 8; ++b)
        acc[k][b] += __shfl_xor(acc[k][b], s, 64);

  // lane jj < 8 stores batch jj, 4 consecutive rows, as one float4
  if (jj < 8) {
    float4 o;
    float v0 = 0.f, v1 = 0.f, v2 = 0.f, v3 = 0.f;
#pragma unroll
    for (int b = 0; b < 8; ++b) {
      bool sel = (jj == b);
      v0 = sel ? acc[0][b] : v0;
      v1 = sel ? acc[1][b] : v1;
      v2 = sel ? acc[2][b] : v2;
      v3 = sel ? acc[3][b] : v3;
    }
    const float* xp = xd + ((size_t)(jj << 8) << 10) + rbase;
    float4 xv = *(const float4*)xp;
    o.x = xv.x * (1.f + fmaxf(v0, 0.f));
    o.y = xv.y * (1.f + fmaxf(v1, 0.f));
    o.z = xv.z * (1.f + fmaxf(v2, 0.f));
    o.w = xv.w * (1.f + fmaxf(v3, 0.f));
    *(float4*)(y + ((size_t)(jj << 8) << 10) + ((size_t)d << 10) + rbase) = o;
  }
}

// Kernel 2: LayerNorm over channel axis d (size 256) per (b, s).
__global__ __launch_bounds__(256)
void ln_kernel(const float* __restrict__ y, const float* __restrict__ gamma,
               const float* __restrict__ beta, float* __restrict__ out) {
  __shared__ float tile[D_][33];
  __shared__ float ps[8][32];
  __shared__ float pq[8][32];
  __shared__ float mu[32];
  __shared__ float rs[32];
  int b = blockIdx.x >> 5;
  int s0 = (blockIdx.x & 31) << 5;
  int t = threadIdx.x;
  int sj = t & 31, dq = t >> 5;
  for (int dd = dq; dd < D_; dd += 8)
    tile[dd][sj] = y[((size_t)b * D_ + dd) * S_ + s0 + sj];
  __syncthreads();
  float sm = 0.f, sq = 0.f;
#pragma unroll 8
  for (int r = 0; r < 32; ++r) {
    float v = tile[dq * 32 + r][sj];
    sm += v;
    sq += v * v;
  }
  ps[dq][sj] = sm;
  pq[dq][sj] = sq;
  __syncthreads();
  if (t < 32) {
    float S = 0.f, Q = 0.f;
#pragma unroll
    for (int qq = 0; qq < 8; ++qq) { S += ps[qq][t]; Q += pq[qq][t]; }
    float mm = S * (1.f / 256.f);
    float var = Q * (1.f / 256.f) - mm * mm;
    mu[t] = mm;
    rs[t] = rsqrtf(var + 1e-5f);
  }
  __syncthreads();
  for (int dd = dq; dd < D_; dd += 8) {
    float v = tile[dd][sj];
    out[((size_t)b * D_ + dd) * S_ + s0 + sj] =
        (v - mu[sj]) * rs[sj] * gamma[dd] + beta[dd];
  }
}

extern "C" void kernel_launch(void* const* d_in, const int* in_sizes, int n_in,
                              void* d_out, int out_size, void* d_ws, size_t ws_size,
                              hipStream_t stream) {
  const float* x = (const float*)d_in[0];
  const float* weight = (const float*)d_in[1];
  const float* gamma = (const float*)d_in[2];
  const float* beta = (const float*)d_in[3];
  float* out = (float*)d_out;
  float* y = (float*)d_ws;  // 8*256*1024 f32 = 8 MB scratch

  lie_mix_kernel<<<4096, 256, 0, stream>>>(x, weight, y);
  ln_kernel<<<256, 256, 0, stream>>>(y, gamma, beta, out);
}

// Round 8
// 134.560 us; speedup vs baseline: 1.1789x; 1.0079x over previous
//
#include <hip/hip_runtime.h>

#define SM 1028
#define D_ 256
#define S_ 1024
#define B_ 8

typedef float f4v __attribute__((ext_vector_type(4)));
#define NTLD(p) __builtin_nontemporal_load((const f4v*)(p))

// Kernel 1: c[b,d,i] = sum_{w<i} x[b,d,w] * weight[d,i,w]; y = x*(1+relu(c))
// R1 geometry (best known: 129 us): grid 4096 = 256 d * 16 row-blocks (64
// rows), heavy-first; block 256 thr = 4 waves; wave = 4 groups x 16 lanes;
// group owns 4 CONSECUTIVE rows; chunk = 64 floats (group-span 256 B of one
// row; straddled tails reused via L1 one iteration later); x staged in LDS,
// xb reads broadcast across the 4 groups (conflict-free).
// NEW: (1) weight loads are NONTEMPORAL (549 MB stream marked evict-first --
// tests L2-allocation-thrash hypothesis for the 4.6 vs 6.5 TB/s read/write
// gap); (2) LDS exactly 32 KB + launch_bounds(256,5) + no manual prefetch
// (VGPR ~75) -> 5 blocks = 20 waves/CU; (3) float4 y stores.
__global__ __launch_bounds__(256, 5)
void lie_mix_kernel(const float* __restrict__ x, const float* __restrict__ weight,
                    float* __restrict__ y) {
  int bid = blockIdx.x;
  int d = bid & 255;
  int bi = 15 - (bid >> 8);   // heavy (large i0) blocks get low blockIdx
  int i0 = bi << 6;           // block rows: [i0, i0+64)

  __shared__ __align__(16) float xs[B_][S_];  // exactly 32 KB -> 5 blocks/CU

  int t = threadIdx.x;
  // stage x[b][d][0 .. i0+64): wlim4 <= 256, one float4 per thread per batch
  int wlim4 = (i0 + 64) >> 2;
#pragma unroll
  for (int bb = 0; bb < B_; ++bb) {
    const float4* src = (const float4*)(x + ((size_t)bb * D_ + d) * S_);
    if (t < wlim4) *(float4*)&xs[bb][t << 2] = src[t];
  }
  __syncthreads();

  int lane = t & 63;
  int wid = t >> 6;
  int g = lane >> 4;                 // group within wave
  int jj = lane & 15;                // lane within group
  int j4 = jj << 2;
  int rbase = i0 + (wid << 4) + (g << 2);   // 4 consecutive rows

  const float* wbase = weight + ((size_t)d * SM + rbase) * SM + j4;

  float acc[4][8];
#pragma unroll
  for (int k = 0; k < 4; ++k)
#pragma unroll
    for (int b = 0; b < 8; ++b) acc[k][b] = 0.f;

  int F = i0 >> 6;  // full 64-elem chunks

  for (int c = 0; c < F; ++c) {
    int w0 = c << 6;
    f4v wc[4];
#pragma unroll
    for (int k = 0; k < 4; ++k)
      wc[k] = NTLD(wbase + (size_t)k * SM + w0);
#pragma unroll
    for (int b = 0; b < 8; ++b) {
      float4 xb = *(const float4*)&xs[b][w0 + j4];
#pragma unroll
      for (int k = 0; k < 4; ++k) {
        acc[k][b] += xb.x * wc[k][0] + xb.y * wc[k][1] +
                     xb.z * wc[k][2] + xb.w * wc[k][3];
      }
    }
  }

  // final masked chunk: w in [i0, i0+64); element e valid iff e < row - i0
  {
    int w0 = i0;
    int lim0 = (wid << 4) + (g << 2);  // rbase - i0
    f4v wm[4];
#pragma unroll
    for (int k = 0; k < 4; ++k) {
      int lim = lim0 + k;
      f4v v = (f4v)(0.f);
      if (j4 < lim) v = NTLD(wbase + (size_t)k * SM + w0);
      if (j4 + 1 >= lim) v[1] = 0.f;
      if (j4 + 2 >= lim) v[2] = 0.f;
      if (j4 + 3 >= lim) v[3] = 0.f;
      wm[k] = v;
    }
#pragma unroll
    for (int b = 0; b < 8; ++b) {
      float4 xb = *(const float4*)&xs[b][w0 + j4];
#pragma unroll
      for (int k = 0; k < 4; ++k) {
        acc[k][b] += xb.x * wm[k][0] + xb.y * wm[k][1] +
                     xb.z * wm[k][2] + xb.w * wm[k][3];
      }
    }
  }

  // radix-16 butterfly (xor 1,2,4,8 stay within the 16-lane group)
#pragma unroll
  for (int s = 1; s < 16; s <<= 1)
#pragma unroll
    for (int k = 0; k < 4; ++k)
#pragma unroll
      for (int b = 0; b < 8; ++b)
        acc[k][b] += __shfl_xor(acc[k][b], s, 64);

  // lane jj < 8 stores batch jj, 4 consecutive rows (s-positions), as float4
  if (jj < 8) {
    float v0 = 0.f, v1 = 0.f, v2 = 0.f, v3 = 0.f;
#pragma unroll
    for (int b = 0; b < 8; ++b) {
      bool sel = (jj == b);
      v0 = sel ? acc[0][b] : v0;
      v1 = sel ? acc[1][b] : v1;
      v2 = sel ? acc[2][b] : v2;
      v3 = sel ? acc[3][b] : v3;
    }
    float4 xv = *(const float4*)&xs[jj][rbase];
    float4 o;
    o.x = xv.x * (1.f + fmaxf(v0, 0.f));
    o.y = xv.y * (1.f + fmaxf(v1, 0.f));
    o.z = xv.z * (1.f + fmaxf(v2, 0.f));
    o.w = xv.w * (1.f + fmaxf(v3, 0.f));
    *(float4*)(y + ((size_t)jj * D_ + d) * S_ + rbase) = o;
  }
}

// Kernel 2: LayerNorm over channel axis d (size 256) per (b, s).
__global__ __launch_bounds__(256)
void ln_kernel(const float* __restrict__ y, const float* __restrict__ gamma,
               const float* __restrict__ beta, float* __restrict__ out) {
  __shared__ float tile[D_][33];
  __shared__ float ps[8][32];
  __shared__ float pq[8][32];
  __shared__ float mu[32];
  __shared__ float rs[32];
  int b = blockIdx.x >> 5;
  int s0 = (blockIdx.x & 31) << 5;
  int t = threadIdx.x;
  int sj = t & 31, dq = t >> 5;
  for (int dd = dq; dd < D_; dd += 8)
    tile[dd][sj] = y[((size_t)b * D_ + dd) * S_ + s0 + sj];
  __syncthreads();
  float sm = 0.f, sq = 0.f;
#pragma unroll 8
  for (int r = 0; r < 32; ++r) {
    float v = tile[dq * 32 + r][sj];
    sm += v;
    sq += v * v;
  }
  ps[dq][sj] = sm;
  pq[dq][sj] = sq;
  __syncthreads();
  if (t < 32) {
    float S = 0.f, Q = 0.f;
#pragma unroll
    for (int qq = 0; qq < 8; ++qq) { S += ps[qq][t]; Q += pq[qq][t]; }
    float mm = S * (1.f / 256.f);
    float var = Q * (1.f / 256.f) - mm * mm;
    mu[t] = mm;
    rs[t] = rsqrtf(var + 1e-5f);
  }
  __syncthreads();
  for (int dd = dq; dd < D_; dd += 8) {
    float v = tile[dd][sj];
    out[((size_t)b * D_ + dd) * S_ + s0 + sj] =
        (v - mu[sj]) * rs[sj] * gamma[dd] + beta[dd];
  }
}

extern "C" void kernel_launch(void* const* d_in, const int* in_sizes, int n_in,
                              void* d_out, int out_size, void* d_ws, size_t ws_size,
                              hipStream_t stream) {
  const float* x = (const float*)d_in[0];
  const float* weight = (const float*)d_in[1];
  const float* gamma = (const float*)d_in[2];
  const float* beta = (const float*)d_in[3];
  float* out = (float*)d_out;
  float* y = (float*)d_ws;  // 8*256*1024 f32 = 8 MB scratch

  lie_mix_kernel<<<4096, 256, 0, stream>>>(x, weight, y);
  ln_kernel<<<256, 256, 0, stream>>>(y, gamma, beta, out);
}

// Round 9
// 131.514 us; speedup vs baseline: 1.2062x; 1.0232x over previous
//
#include <hip/hip_runtime.h>

#define SM 1028
#define D_ 256
#define S_ 1024
#define B_ 8

typedef float f4v __attribute__((ext_vector_type(4)));
#define NTLD(p) __builtin_nontemporal_load((const f4v*)(p))

// Kernel 1: c[b,d,i] = sum_{w<i} x[b,d,w] * weight[d,i,w]; y = x*(1+relu(c))
// Best-of-all-rounds assembly:
//  - R1 geometry (129 us best): grid 4096 = 256 d x 16 row-blocks (64 rows),
//    heavy-first; block = 4 waves; wave = 4 groups x 16 lanes; group owns 4
//    CONSECUTIVE rows; chunk = 64 floats (256 B span per row; straddle tails
//    reused next iteration via L1/L2); x staged in LDS, xb broadcast reads.
//  - explicit 2-deep register prefetch (R1 feature whose removal cost ~6 us
//    in R7/R8 -- the only surviving positive mechanism of rounds 2-8).
//  - predicated prefetch of the final masked chunk: lanes beyond the causal
//    limit issue NO load (saves ~33 MB tail over-fetch R1 paid), and the
//    masked chunk consumes the prefetched registers with zero reloads.
//  - nontemporal weight loads (null in isolation, free), float4 y stores.
// Occupancy stays 4 blocks/CU (16 waves) -- 20 waves proved null (R7/R8) and
// (256,4) keeps the prefetch live-range spill-free.
__global__ __launch_bounds__(256, 4)
void lie_mix_kernel(const float* __restrict__ x, const float* __restrict__ weight,
                    float* __restrict__ y) {
  int bid = blockIdx.x;
  int d = bid & 255;
  int bi = 15 - (bid >> 8);   // heavy (large i0) blocks get low blockIdx
  int i0 = bi << 6;           // block rows: [i0, i0+64)

  __shared__ __align__(16) float xs[B_][S_];

  int t = threadIdx.x;
  // stage x[b][d][0 .. i0+64) into LDS (one float4/thread/batch, coalesced)
  int wlim4 = (i0 + 64) >> 2;
#pragma unroll
  for (int bb = 0; bb < B_; ++bb) {
    const float4* src = (const float4*)(x + ((size_t)bb * D_ + d) * S_);
    if (t < wlim4) *(float4*)&xs[bb][t << 2] = src[t];
  }
  __syncthreads();

  int lane = t & 63;
  int wid = t >> 6;
  int g = lane >> 4;                 // group within wave
  int jj = lane & 15;                // lane within group
  int j4 = jj << 2;
  int rbase = i0 + (wid << 4) + (g << 2);   // 4 consecutive rows
  int lim0 = (wid << 4) + (g << 2);         // rbase - i0

  const float* wbase = weight + ((size_t)d * SM + rbase) * SM + j4;

  float acc[4][8];
#pragma unroll
  for (int k = 0; k < 4; ++k)
#pragma unroll
    for (int b = 0; b < 8; ++b) acc[k][b] = 0.f;

#define FMA_CHUNK(buf, w0)                                               \
  do {                                                                   \
    _Pragma("unroll") for (int b = 0; b < 8; ++b) {                      \
      float4 xb = *(const float4*)&xs[b][(w0) + j4];                     \
      _Pragma("unroll") for (int k = 0; k < 4; ++k) {                    \
        acc[k][b] += xb.x * buf[k][0] + xb.y * buf[k][1] +               \
                     xb.z * buf[k][2] + xb.w * buf[k][3];                \
      }                                                                  \
    }                                                                    \
  } while (0)

  int F = i0 >> 6;  // full 64-elem chunks

  f4v wc[4], wn[4];
#pragma unroll
  for (int k = 0; k < 4; ++k) wc[k] = NTLD(wbase + (size_t)k * SM);

  // main loop with 1-chunk register prefetch (chunks 0 .. F-2 compute)
  for (int c = 0; c + 1 < F; ++c) {
#pragma unroll
    for (int k = 0; k < 4; ++k)
      wn[k] = NTLD(wbase + (size_t)k * SM + ((c + 1) << 6));
    FMA_CHUNK(wc, c << 6);
#pragma unroll
    for (int k = 0; k < 4; ++k) wc[k] = wn[k];
  }

  if (F > 0) {
    // predicated prefetch of the masked chunk F (no fetch past the triangle)
#pragma unroll
    for (int k = 0; k < 4; ++k) {
      int lim = lim0 + k;
      f4v v = (f4v)(0.f);
      if (j4 < lim) v = NTLD(wbase + (size_t)k * SM + (F << 6));
      if (j4 + 1 >= lim) v[1] = 0.f;
      if (j4 + 2 >= lim) v[2] = 0.f;
      if (j4 + 3 >= lim) v[3] = 0.f;
      wn[k] = v;
    }
    FMA_CHUNK(wc, (F - 1) << 6);   // compute chunk F-1
#pragma unroll
    for (int k = 0; k < 4; ++k) wc[k] = wn[k];
  } else {
    // F == 0: wc holds chunk 0 == the masked chunk; mask in-register
#pragma unroll
    for (int k = 0; k < 4; ++k) {
      int lim = lim0 + k;
      if (j4 >= lim) wc[k][0] = 0.f;
      if (j4 + 1 >= lim) wc[k][1] = 0.f;
      if (j4 + 2 >= lim) wc[k][2] = 0.f;
      if (j4 + 3 >= lim) wc[k][3] = 0.f;
    }
  }

  FMA_CHUNK(wc, F << 6);           // final masked chunk, zero extra loads

  // radix-16 butterfly (xor 1,2,4,8 stay within the 16-lane group)
#pragma unroll
  for (int s = 1; s < 16; s <<= 1)
#pragma unroll
    for (int k = 0; k < 4; ++k)
#pragma unroll
      for (int b = 0; b < 8; ++b)
        acc[k][b] += __shfl_xor(acc[k][b], s, 64);

  // lane jj < 8 stores batch jj, 4 consecutive rows, as one float4
  if (jj < 8) {
    float v0 = 0.f, v1 = 0.f, v2 = 0.f, v3 = 0.f;
#pragma unroll
    for (int b = 0; b < 8; ++b) {
      bool sel = (jj == b);
      v0 = sel ? acc[0][b] : v0;
      v1 = sel ? acc[1][b] : v1;
      v2 = sel ? acc[2][b] : v2;
      v3 = sel ? acc[3][b] : v3;
    }
    float4 xv = *(const float4*)&xs[jj][rbase];
    float4 o;
    o.x = xv.x * (1.f + fmaxf(v0, 0.f));
    o.y = xv.y * (1.f + fmaxf(v1, 0.f));
    o.z = xv.z * (1.f + fmaxf(v2, 0.f));
    o.w = xv.w * (1.f + fmaxf(v3, 0.f));
    *(float4*)(y + ((size_t)jj * D_ + d) * S_ + rbase) = o;
  }
#undef FMA_CHUNK
}

// Kernel 2: LayerNorm over channel axis d (size 256) per (b, s).
__global__ __launch_bounds__(256)
void ln_kernel(const float* __restrict__ y, const float* __restrict__ gamma,
               const float* __restrict__ beta, float* __restrict__ out) {
  __shared__ float tile[D_][33];
  __shared__ float ps[8][32];
  __shared__ float pq[8][32];
  __shared__ float mu[32];
  __shared__ float rs[32];
  int b = blockIdx.x >> 5;
  int s0 = (blockIdx.x & 31) << 5;
  int t = threadIdx.x;
  int sj = t & 31, dq = t >> 5;
  for (int dd = dq; dd < D_; dd += 8)
    tile[dd][sj] = y[((size_t)b * D_ + dd) * S_ + s0 + sj];
  __syncthreads();
  float sm = 0.f, sq = 0.f;
#pragma unroll 8
  for (int r = 0; r < 32; ++r) {
    float v = tile[dq * 32 + r][sj];
    sm += v;
    sq += v * v;
  }
  ps[dq][sj] = sm;
  pq[dq][sj] = sq;
  __syncthreads();
  if (t < 32) {
    float S = 0.f, Q = 0.f;
#pragma unroll
    for (int qq = 0; qq < 8; ++qq) { S += ps[qq][t]; Q += pq[qq][t]; }
    float mm = S * (1.f / 256.f);
    float var = Q * (1.f / 256.f) - mm * mm;
    mu[t] = mm;
    rs[t] = rsqrtf(var + 1e-5f);
  }
  __syncthreads();
  for (int dd = dq; dd < D_; dd += 8) {
    float v = tile[dd][sj];
    out[((size_t)b * D_ + dd) * S_ + s0 + sj] =
        (v - mu[sj]) * rs[sj] * gamma[dd] + beta[dd];
  }
}

extern "C" void kernel_launch(void* const* d_in, const int* in_sizes, int n_in,
                              void* d_out, int out_size, void* d_ws, size_t ws_size,
                              hipStream_t stream) {
  const float* x = (const float*)d_in[0];
  const float* weight = (const float*)d_in[1];
  const float* gamma = (const float*)d_in[2];
  const float* beta = (const float*)d_in[3];
  float* out = (float*)d_out;
  float* y = (float*)d_ws;  // 8*256*1024 f32 = 8 MB scratch

  lie_mix_kernel<<<4096, 256, 0, stream>>>(x, weight, y);
  ln_kernel<<<256, 256, 0, stream>>>(y, gamma, beta, out);
}